// Round 12
// baseline (3857.498 us; speedup 1.0000x reference)
//
#include <hip/hip_runtime.h>
#include <hip/hip_bf16.h>

// RNN: B=1024, T=512, H=128, +4 autoregressive steps -> out (1024, 516)
// Round 12: epilogue diet on R11 (64 blk x 8 waves, fp16, XOR swizzle).
//  - W/b/w0 pre-scaled by 2*log2(e): MFMA acc IS the exp2 argument ->
//    tanh = 1 - 2/(v_exp(acc)+1); z+z and *log2e removed from epilogue.
//  - epilogue phase-batched (4 z, 4 exp, 4 rcp, ...) to overlap trans latency.
//  - per-wave rotated bfrag read order (kf0 = wv&3).
//  Cost model (verified R11): step = LDS drain 384 + last-wave epilogue tail
//  + barrier; this round attacks the tail.

#define BB 1024
#define TT 512
#define HH 128
#define TOUT 516
#define BM 16          // batch rows per block
#define XSTR 513       // xs stride (dwords)
#define YSTR 517       // ybuf stride (dwords)
#define PQS 36         // pq row stride (dwords)
#define TWOLOG2E 2.885390082f

typedef __attribute__((ext_vector_type(8))) _Float16 f16x8;
typedef __attribute__((ext_vector_type(4))) float f32x4;

#define MFMA16(A_, B_, C_) __builtin_amdgcn_mfma_f32_16x16x32_f16(A_, B_, C_, 0, 0, 0)

__global__ void detect_dtype(const void* w, int* flag) {
    const int lane = threadIdx.x;  // 64 threads
    const __hip_bfloat16* p = (const __hip_bfloat16*)w;
    const float v0 = __bfloat162float(p[lane]);
    const float v1 = __bfloat162float(p[64 + lane]);
    const bool bad = !(fabsf(v0) < 100.0f) || !(fabsf(v1) < 100.0f);
    const unsigned long long m = __ballot(bad);
    if (lane == 0) *flag = (__popcll(m) > 4) ? 1 : 0;  // 1 => data is fp32
}

template <bool F32>
__device__ __forceinline__ float ldg(const void* p, int idx) {
    if (F32) return ((const float*)p)[idx];
    return __bfloat162float(((const __hip_bfloat16*)p)[idx]);
}

// sum of pq row [0..31] (16B-aligned)
__device__ __forceinline__ float red32(const float* pqrow) {
    const f32x4* v = (const f32x4*)pqrow;
    const f32x4 s = ((v[0] + v[1]) + (v[2] + v[3])) + ((v[4] + v[5]) + (v[6] + v[7]));
    return (s[0] + s[1]) + (s[2] + s[3]);
}

// One RNN step. T_: timestep; CUR_: h read buffer; WRITEY_: wave7 dec tile
// emits y[T_-1]; DOPQ_: lanes write decoder partials to pq (tail);
// READX_: prefetch xs[T_+1]; TAILX_: xv from pq reduce (feedback).
// hbuf swizzle: logical 16B-chunk c of row n lives at physical chunk (c^n)&15.
// acc accumulates 2*log2e*z; h = 1 - 2/(exp2(acc)+1).
#define STEP(T_, CUR_, WRITEY_, DOPQ_, READX_, TAILX_) do {                     \
    f16x8 bfrag[4];                                                             \
    _Pragma("unroll")                                                           \
    for (int kk = 0; kk < 4; ++kk) {                                            \
        const int kf = (kk + wv) & 3;                                           \
        bfrag[kf] = *(const f16x8*)&hbuf[CUR_][n][((((kf << 2) | q) ^ n) & 15) << 3]; \
    }                                                                           \
    float xnext = 0.0f;                                                         \
    if (READX_) xnext = xs[n][(T_) + 1];                                        \
    float xv;                                                                   \
    if (TAILX_) xv = red32(&pq[((T_) - 1) & 1][n][0]) + dbv;                    \
    else        xv = xpref;                                                     \
    f32x4 acc0, acc1;                                                           \
    _Pragma("unroll")                                                           \
    for (int r = 0; r < 4; ++r) acc0[r] = fmaf(xv, w0v[r], bsum[r]);            \
    acc1 = (f32x4){0.f, 0.f, 0.f, 0.f};                                         \
    acc0 = MFMA16(wa[0], bfrag[0], acc0);                                       \
    acc1 = MFMA16(wa[1], bfrag[1], acc1);                                       \
    acc0 = MFMA16(wa[2], bfrag[2], acc0);                                       \
    acc1 = MFMA16(wa[3], bfrag[3], acc1);                                       \
    if (isw7 && (WRITEY_)) {  /* dec tile: y[T_-1] = dec . h_old */             \
        f32x4 aD0 = (f32x4){0.f, 0.f, 0.f, 0.f};                                \
        f32x4 aD1 = (f32x4){0.f, 0.f, 0.f, 0.f};                                \
        aD0 = MFMA16(wa_d[0], bfrag[0], aD0);                                   \
        aD1 = MFMA16(wa_d[1], bfrag[1], aD1);                                   \
        aD0 = MFMA16(wa_d[2], bfrag[2], aD0);                                   \
        aD1 = MFMA16(wa_d[3], bfrag[3], aD1);                                   \
        const float yp = aD0[0] + aD1[0] + dbv;                                 \
        if (q == 0) ybuf[n][(T_) - 1] = yp;                                     \
    }                                                                           \
    float zs[4], ex[4], rc[4], hv[4];                                           \
    _Pragma("unroll")                                                           \
    for (int r = 0; r < 4; ++r) zs[r] = acc0[r] + acc1[r];                      \
    _Pragma("unroll")                                                           \
    for (int r = 0; r < 4; ++r) ex[r] = __builtin_amdgcn_exp2f(zs[r]);          \
    _Pragma("unroll")                                                           \
    for (int r = 0; r < 4; ++r) rc[r] = __builtin_amdgcn_rcpf(ex[r] + 1.0f);    \
    _Pragma("unroll")                                                           \
    for (int r = 0; r < 4; ++r) hv[r] = fmaf(-2.0f, rc[r], 1.0f);               \
    float p = 0.0f;                                                             \
    if (DOPQ_) {                                                                \
        _Pragma("unroll")                                                       \
        for (int r = 0; r < 4; ++r) p = fmaf(decv[r], hv[r], p);                \
    }                                                                           \
    uint2 pk;                                                                   \
    pk.x = __builtin_bit_cast(unsigned, __builtin_amdgcn_cvt_pkrtz(hv[0], hv[1])); \
    pk.y = __builtin_bit_cast(unsigned, __builtin_amdgcn_cvt_pkrtz(hv[2], hv[3])); \
    *(uint2*)&hbuf[(CUR_) ^ 1][n][((((2 * wv + (q >> 1)) ^ n) & 15) << 3) + ((q & 1) << 2)] = pk; \
    if (DOPQ_) pq[(T_) & 1][n][wv * 4 + q] = p;                                 \
    if (READX_) xpref = xnext;                                                  \
    __syncthreads();                                                            \
} while (0)

template <bool F32>
__device__ void rnn_body(const void* __restrict__ xg, const void* __restrict__ h0,
                         const void* __restrict__ w0, const void* __restrict__ b0,
                         const void* __restrict__ W,  const void* __restrict__ bw,
                         const void* __restrict__ dw, const void* __restrict__ db,
                         void* __restrict__ out,
                         float (*xs)[XSTR], float (*ybuf)[YSTR],
                         _Float16 (*hbuf)[BM][HH], float (*pq)[BM][PQS])
{
    const int tid  = threadIdx.x;
    const int lane = tid & 63;
    const int wv   = tid >> 6;        // 0..7 (= m-tile index)
    const int q    = lane >> 4;       // 0..3
    const int n    = lane & 15;       // batch col / A-row-in-tile
    const int row0 = blockIdx.x * BM;
    const bool isw7 = (wv == 7);      // wave-uniform

    // stage x (fp32 in LDS)
    for (int idx = tid; idx < BM * TT; idx += 512) {
        const int rr = idx >> 9, t2 = idx & (TT - 1);
        xs[rr][t2] = ldg<F32>(xg, (row0 + rr) * TT + t2);
    }
    // stage h0 as fp16 (swizzled: chunk c of row rr -> (c^rr)&15)
    for (int idx = tid; idx < BM * HH; idx += 512) {
        const int rr = idx >> 7, ii = idx & (HH - 1);
        const int po = ((((ii >> 3) ^ rr) & 15) << 3) + (ii & 7);
        hbuf[0][rr][po] = (_Float16)ldg<F32>(h0, (row0 + rr) * HH + ii);
    }

    // preload W fragments (A-operand: A[m=lane&15][k=q*8+j]) as fp16,
    // PRE-SCALED by 2*log2e so the accumulator is the exp2 argument.
    f16x8 wa[4];
    {
        const int ia = wv * 16 + n;   // W row (output unit)
        #pragma unroll
        for (int kf = 0; kf < 4; ++kf) {
            const int kb = kf * 32 + q * 8;
            f16x8 fr;
            #pragma unroll
            for (int j = 0; j < 8; ++j)
                fr[j] = (_Float16)(TWOLOG2E * ldg<F32>(W, ia * HH + kb + j));
            wa[kf] = fr;
        }
    }
    // dec tile (wave 7): A row 0 = dec_w (UNscaled - operates on h), rows 1..15 = 0
    f16x8 wa_d[4] = {};
    if (isw7) {
        #pragma unroll
        for (int kf = 0; kf < 4; ++kf) {
            const int kb = kf * 32 + q * 8;
            f16x8 fr = {};
            if (n == 0) {
                #pragma unroll
                for (int j = 0; j < 8; ++j) fr[j] = (_Float16)ldg<F32>(dw, kb + j);
            }
            wa_d[kf] = fr;
        }
    }
    // epilogue constants (C-layout rows: i = wv*16 + q*4 + r), pre-scaled
    float bsum[4], w0v[4], decv[4];
    #pragma unroll
    for (int r = 0; r < 4; ++r) {
        const int ic = wv * 16 + q * 4 + r;
        bsum[r] = TWOLOG2E * (ldg<F32>(b0, ic) + ldg<F32>(bw, ic));
        w0v[r]  = TWOLOG2E * ldg<F32>(w0, ic);
        decv[r] = ldg<F32>(dw, ic);
    }
    const float dbv = ldg<F32>(db, 0);

    __syncthreads();

    float xpref = xs[n][0];

    // t = 0: no y yet, no pq
    STEP(0, 0, false, false, true, false);

    // main: t = 1..510, compile-time cur (odd reads buf1, even reads buf0)
    #pragma unroll 1
    for (int t = 1; t < 511; t += 2) {
        STEP(t,     1, true, false, true, false);
        STEP(t + 1, 0, true, false, true, false);
    }

    // t = 511: last x step; start pq for tail feedback
    STEP(511, 1, true, true, false, false);

    // tail: t = 512..515, xv = y[t-1] via pq reduce
    #pragma unroll 1
    for (int t = 512; t < 516; ++t) {
        STEP(t, t & 1, true, true, false, true);
    }

    // final y[515]
    if (isw7 && q == 0)
        ybuf[n][TOUT - 1] = red32(&pq[(TOUT - 1) & 1][n][0]) + dbv;
    __syncthreads();

    // flush outputs (coalesced over t)
    for (int rr = 0; rr < BM; ++rr)
        for (int t2 = tid; t2 < TOUT; t2 += 512) {
            const int o = (row0 + rr) * TOUT + t2;
            const float y = ybuf[rr][t2];
            if (F32) ((float*)out)[o] = y;
            else     ((__hip_bfloat16*)out)[o] = __float2bfloat16(y);
        }
}

__global__ __launch_bounds__(512, 2)
void rnn_mfma(const void* __restrict__ xg, const void* __restrict__ h0,
              const void* __restrict__ w0, const void* __restrict__ b0,
              const void* __restrict__ W,  const void* __restrict__ bw,
              const void* __restrict__ dw, const void* __restrict__ db,
              void* __restrict__ out, const int* __restrict__ flag)
{
    __shared__ float xs[BM][XSTR];                          // 32.8 KB
    __shared__ float ybuf[BM][YSTR];                        // 33.1 KB
    __shared__ __align__(16) _Float16 hbuf[2][BM][HH];      // 8 KB
    __shared__ __align__(16) float pq[2][BM][PQS];          // 4.6 KB

    const int f = *(volatile const int*)flag;  // block-uniform
    if (f) rnn_body<true >(xg, h0, w0, b0, W, bw, dw, db, out, xs, ybuf, hbuf, pq);
    else   rnn_body<false>(xg, h0, w0, b0, W, bw, dw, db, out, xs, ybuf, hbuf, pq);
}

extern "C" void kernel_launch(void* const* d_in, const int* in_sizes, int n_in,
                              void* d_out, int out_size, void* d_ws, size_t ws_size,
                              hipStream_t stream) {
    int* flag = (int*)d_ws;
    detect_dtype<<<1, 64, 0, stream>>>(d_in[4], flag);  // probe fc_w
    rnn_mfma<<<BB / BM, 512, 0, stream>>>(d_in[0], d_in[1], d_in[2], d_in[3],
                                          d_in[4], d_in[5], d_in[6], d_in[7],
                                          d_out, flag);
}

// Round 13
// 212.777 us; speedup vs baseline: 18.1293x; 18.1293x over previous
//
#include <hip/hip_runtime.h>
#include <hip/hip_bf16.h>

// RNN: B=1024, T=512, H=128, +4 autoregressive steps -> out (1024, 516)
// Round 13: R12 minus the scratch-spill bug. R12's per-wave rotated bfrag
// order (kf=(kk+wv)&3, runtime index) demoted bfrag[] to scratch -> 23x
// regression (VGPR 52->96, WRITE_SIZE 2x = the scratch signature).
// Reverted to fixed kf order. Kept from R12:
//  - W/b/w0 pre-scaled by 2*log2(e): MFMA acc IS the exp2 argument.
//  - phase-batched epilogue (4 z, 4 exp, 4 rcp, 4 fma).
//  - fp16 pipeline + XOR-swizzled hbuf + v_cvt_pkrtz packing (R11).

#define BB 1024
#define TT 512
#define HH 128
#define TOUT 516
#define BM 16          // batch rows per block
#define XSTR 513       // xs stride (dwords)
#define YSTR 517       // ybuf stride (dwords)
#define PQS 36         // pq row stride (dwords)
#define TWOLOG2E 2.885390082f

typedef __attribute__((ext_vector_type(8))) _Float16 f16x8;
typedef __attribute__((ext_vector_type(4))) float f32x4;

#define MFMA16(A_, B_, C_) __builtin_amdgcn_mfma_f32_16x16x32_f16(A_, B_, C_, 0, 0, 0)

__global__ void detect_dtype(const void* w, int* flag) {
    const int lane = threadIdx.x;  // 64 threads
    const __hip_bfloat16* p = (const __hip_bfloat16*)w;
    const float v0 = __bfloat162float(p[lane]);
    const float v1 = __bfloat162float(p[64 + lane]);
    const bool bad = !(fabsf(v0) < 100.0f) || !(fabsf(v1) < 100.0f);
    const unsigned long long m = __ballot(bad);
    if (lane == 0) *flag = (__popcll(m) > 4) ? 1 : 0;  // 1 => data is fp32
}

template <bool F32>
__device__ __forceinline__ float ldg(const void* p, int idx) {
    if (F32) return ((const float*)p)[idx];
    return __bfloat162float(((const __hip_bfloat16*)p)[idx]);
}

// sum of pq row [0..31] (16B-aligned)
__device__ __forceinline__ float red32(const float* pqrow) {
    const f32x4* v = (const f32x4*)pqrow;
    const f32x4 s = ((v[0] + v[1]) + (v[2] + v[3])) + ((v[4] + v[5]) + (v[6] + v[7]));
    return (s[0] + s[1]) + (s[2] + s[3]);
}

// One RNN step. T_: timestep; CUR_: h read buffer; WRITEY_: wave7 dec tile
// emits y[T_-1]; DOPQ_: lanes write decoder partials to pq (tail);
// READX_: prefetch xs[T_+1]; TAILX_: xv from pq reduce (feedback).
// hbuf swizzle: logical 16B-chunk c of row n lives at physical chunk (c^n)&15.
// acc accumulates 2*log2e*z; h = 1 - 2/(exp2(acc)+1).
#define STEP(T_, CUR_, WRITEY_, DOPQ_, READX_, TAILX_) do {                     \
    f16x8 bfrag[4];                                                             \
    _Pragma("unroll")                                                           \
    for (int kf = 0; kf < 4; ++kf)                                              \
        bfrag[kf] = *(const f16x8*)&hbuf[CUR_][n][((((kf << 2) | q) ^ n) & 15) << 3]; \
    float xnext = 0.0f;                                                         \
    if (READX_) xnext = xs[n][(T_) + 1];                                        \
    float xv;                                                                   \
    if (TAILX_) xv = red32(&pq[((T_) - 1) & 1][n][0]) + dbv;                    \
    else        xv = xpref;                                                     \
    f32x4 acc0, acc1;                                                           \
    _Pragma("unroll")                                                           \
    for (int r = 0; r < 4; ++r) acc0[r] = fmaf(xv, w0v[r], bsum[r]);            \
    acc1 = (f32x4){0.f, 0.f, 0.f, 0.f};                                         \
    acc0 = MFMA16(wa[0], bfrag[0], acc0);                                       \
    acc1 = MFMA16(wa[1], bfrag[1], acc1);                                       \
    acc0 = MFMA16(wa[2], bfrag[2], acc0);                                       \
    acc1 = MFMA16(wa[3], bfrag[3], acc1);                                       \
    if (isw7 && (WRITEY_)) {  /* dec tile: y[T_-1] = dec . h_old */             \
        f32x4 aD0 = (f32x4){0.f, 0.f, 0.f, 0.f};                                \
        f32x4 aD1 = (f32x4){0.f, 0.f, 0.f, 0.f};                                \
        aD0 = MFMA16(wa_d[0], bfrag[0], aD0);                                   \
        aD1 = MFMA16(wa_d[1], bfrag[1], aD1);                                   \
        aD0 = MFMA16(wa_d[2], bfrag[2], aD0);                                   \
        aD1 = MFMA16(wa_d[3], bfrag[3], aD1);                                   \
        const float yp = aD0[0] + aD1[0] + dbv;                                 \
        if (q == 0) ybuf[n][(T_) - 1] = yp;                                     \
    }                                                                           \
    float zs[4], ex[4], rc[4], hv[4];                                           \
    _Pragma("unroll")                                                           \
    for (int r = 0; r < 4; ++r) zs[r] = acc0[r] + acc1[r];                      \
    _Pragma("unroll")                                                           \
    for (int r = 0; r < 4; ++r) ex[r] = __builtin_amdgcn_exp2f(zs[r]);          \
    _Pragma("unroll")                                                           \
    for (int r = 0; r < 4; ++r) rc[r] = __builtin_amdgcn_rcpf(ex[r] + 1.0f);    \
    _Pragma("unroll")                                                           \
    for (int r = 0; r < 4; ++r) hv[r] = fmaf(-2.0f, rc[r], 1.0f);               \
    float p = 0.0f;                                                             \
    if (DOPQ_) {                                                                \
        _Pragma("unroll")                                                       \
        for (int r = 0; r < 4; ++r) p = fmaf(decv[r], hv[r], p);                \
    }                                                                           \
    uint2 pk;                                                                   \
    pk.x = __builtin_bit_cast(unsigned, __builtin_amdgcn_cvt_pkrtz(hv[0], hv[1])); \
    pk.y = __builtin_bit_cast(unsigned, __builtin_amdgcn_cvt_pkrtz(hv[2], hv[3])); \
    *(uint2*)&hbuf[(CUR_) ^ 1][n][((((2 * wv + (q >> 1)) ^ n) & 15) << 3) + ((q & 1) << 2)] = pk; \
    if (DOPQ_) pq[(T_) & 1][n][wv * 4 + q] = p;                                 \
    if (READX_) xpref = xnext;                                                  \
    __syncthreads();                                                            \
} while (0)

template <bool F32>
__device__ void rnn_body(const void* __restrict__ xg, const void* __restrict__ h0,
                         const void* __restrict__ w0, const void* __restrict__ b0,
                         const void* __restrict__ W,  const void* __restrict__ bw,
                         const void* __restrict__ dw, const void* __restrict__ db,
                         void* __restrict__ out,
                         float (*xs)[XSTR], float (*ybuf)[YSTR],
                         _Float16 (*hbuf)[BM][HH], float (*pq)[BM][PQS])
{
    const int tid  = threadIdx.x;
    const int lane = tid & 63;
    const int wv   = tid >> 6;        // 0..7 (= m-tile index)
    const int q    = lane >> 4;       // 0..3
    const int n    = lane & 15;       // batch col / A-row-in-tile
    const int row0 = blockIdx.x * BM;
    const bool isw7 = (wv == 7);      // wave-uniform

    // stage x (fp32 in LDS)
    for (int idx = tid; idx < BM * TT; idx += 512) {
        const int rr = idx >> 9, t2 = idx & (TT - 1);
        xs[rr][t2] = ldg<F32>(xg, (row0 + rr) * TT + t2);
    }
    // stage h0 as fp16 (swizzled: chunk c of row rr -> (c^rr)&15)
    for (int idx = tid; idx < BM * HH; idx += 512) {
        const int rr = idx >> 7, ii = idx & (HH - 1);
        const int po = ((((ii >> 3) ^ rr) & 15) << 3) + (ii & 7);
        hbuf[0][rr][po] = (_Float16)ldg<F32>(h0, (row0 + rr) * HH + ii);
    }

    // preload W fragments (A-operand: A[m=lane&15][k=q*8+j]) as fp16,
    // PRE-SCALED by 2*log2e so the accumulator is the exp2 argument.
    f16x8 wa[4];
    {
        const int ia = wv * 16 + n;   // W row (output unit)
        #pragma unroll
        for (int kf = 0; kf < 4; ++kf) {
            const int kb = kf * 32 + q * 8;
            f16x8 fr;
            #pragma unroll
            for (int j = 0; j < 8; ++j)
                fr[j] = (_Float16)(TWOLOG2E * ldg<F32>(W, ia * HH + kb + j));
            wa[kf] = fr;
        }
    }
    // dec tile (wave 7): A row 0 = dec_w (UNscaled - operates on h), rows 1..15 = 0
    f16x8 wa_d[4] = {};
    if (isw7) {
        #pragma unroll
        for (int kf = 0; kf < 4; ++kf) {
            const int kb = kf * 32 + q * 8;
            f16x8 fr = {};
            if (n == 0) {
                #pragma unroll
                for (int j = 0; j < 8; ++j) fr[j] = (_Float16)ldg<F32>(dw, kb + j);
            }
            wa_d[kf] = fr;
        }
    }
    // epilogue constants (C-layout rows: i = wv*16 + q*4 + r), pre-scaled
    float bsum[4], w0v[4], decv[4];
    #pragma unroll
    for (int r = 0; r < 4; ++r) {
        const int ic = wv * 16 + q * 4 + r;
        bsum[r] = TWOLOG2E * (ldg<F32>(b0, ic) + ldg<F32>(bw, ic));
        w0v[r]  = TWOLOG2E * ldg<F32>(w0, ic);
        decv[r] = ldg<F32>(dw, ic);
    }
    const float dbv = ldg<F32>(db, 0);

    __syncthreads();

    float xpref = xs[n][0];

    // t = 0: no y yet, no pq
    STEP(0, 0, false, false, true, false);

    // main: t = 1..510, compile-time cur (odd reads buf1, even reads buf0)
    #pragma unroll 1
    for (int t = 1; t < 511; t += 2) {
        STEP(t,     1, true, false, true, false);
        STEP(t + 1, 0, true, false, true, false);
    }

    // t = 511: last x step; start pq for tail feedback
    STEP(511, 1, true, true, false, false);

    // tail: t = 512..515, xv = y[t-1] via pq reduce
    #pragma unroll 1
    for (int t = 512; t < 516; ++t) {
        STEP(t, t & 1, true, true, false, true);
    }

    // final y[515]
    if (isw7 && q == 0)
        ybuf[n][TOUT - 1] = red32(&pq[(TOUT - 1) & 1][n][0]) + dbv;
    __syncthreads();

    // flush outputs (coalesced over t)
    for (int rr = 0; rr < BM; ++rr)
        for (int t2 = tid; t2 < TOUT; t2 += 512) {
            const int o = (row0 + rr) * TOUT + t2;
            const float y = ybuf[rr][t2];
            if (F32) ((float*)out)[o] = y;
            else     ((__hip_bfloat16*)out)[o] = __float2bfloat16(y);
        }
}

__global__ __launch_bounds__(512, 2)
void rnn_mfma(const void* __restrict__ xg, const void* __restrict__ h0,
              const void* __restrict__ w0, const void* __restrict__ b0,
              const void* __restrict__ W,  const void* __restrict__ bw,
              const void* __restrict__ dw, const void* __restrict__ db,
              void* __restrict__ out, const int* __restrict__ flag)
{
    __shared__ float xs[BM][XSTR];                          // 32.8 KB
    __shared__ float ybuf[BM][YSTR];                        // 33.1 KB
    __shared__ __align__(16) _Float16 hbuf[2][BM][HH];      // 8 KB
    __shared__ __align__(16) float pq[2][BM][PQS];          // 4.6 KB

    const int f = *(volatile const int*)flag;  // block-uniform
    if (f) rnn_body<true >(xg, h0, w0, b0, W, bw, dw, db, out, xs, ybuf, hbuf, pq);
    else   rnn_body<false>(xg, h0, w0, b0, W, bw, dw, db, out, xs, ybuf, hbuf, pq);
}

extern "C" void kernel_launch(void* const* d_in, const int* in_sizes, int n_in,
                              void* d_out, int out_size, void* d_ws, size_t ws_size,
                              hipStream_t stream) {
    int* flag = (int*)d_ws;
    detect_dtype<<<1, 64, 0, stream>>>(d_in[4], flag);  // probe fc_w
    rnn_mfma<<<BB / BM, 512, 0, stream>>>(d_in[0], d_in[1], d_in[2], d_in[3],
                                          d_in[4], d_in[5], d_in[6], d_in[7],
                                          d_out, flag);
}